// Round 8
// baseline (163.381 us; speedup 1.0000x reference)
//
#include <hip/hip_runtime.h>
#include <hip/hip_bf16.h>

// Problem constants: B=2, S=2048, D=1024, H=16, HD=64, M = B*S = 4096

typedef __attribute__((ext_vector_type(8))) short short8;   // 8 bf16 = 4 VGPR
typedef __attribute__((ext_vector_type(4))) short short4v;  // 4 bf16
typedef __attribute__((ext_vector_type(4))) float f32x4;    // MFMA C/D frag

static __device__ __forceinline__ short f2bf(float f) {
    union { float f; unsigned u; } c; c.f = f;
    unsigned r = c.u + 0x7fff + ((c.u >> 16) & 1);   // RNE
    return (short)(r >> 16);
}

// packed f32x2 -> bf16x2 (v_cvt_pk_bf16_f32)
static __device__ __forceinline__ unsigned pk_bf16(float a, float b) {
    union { __hip_bfloat162 h; unsigned u; } c;
    c.h = __float22bfloat162_rn(make_float2(a, b));
    return c.u;
}

// async global -> LDS, 16B per lane (global_load_lds_dwordx4).
typedef const void __attribute__((address_space(1)))* gas_ptr;
typedef void __attribute__((address_space(3)))* las_ptr;
static __device__ __forceinline__ void gload16(const void* g, void* l) {
    __builtin_amdgcn_global_load_lds((gas_ptr)g, (las_ptr)l, 16, 0, 0);
}

// ---------------------------------------------------------------------------
// prep: merged f32->bf16 input conversion (3 x 4M elems) + weight transpose
// (4 x W[K][N] f32 -> Wt[N][K] bf16). One dispatch, 10240 blocks.
// ---------------------------------------------------------------------------
__global__ __launch_bounds__(256) void prep(
    const float* __restrict__ X0, const float* __restrict__ X1,
    const float* __restrict__ X2, short* __restrict__ Abf,
    const float* __restrict__ W0, const float* __restrict__ W1,
    const float* __restrict__ W2, const float* __restrict__ W3,
    short* __restrict__ Wt)
{
    __shared__ float tile[32][33];
    const int bid = blockIdx.x;
    if (bid < 6144) {           // --- tobf16: 2048 blocks per input ---
        const int zz = bid >> 11, xb = bid & 2047;
        const float* X = zz == 0 ? X0 : zz == 1 ? X1 : X2;
        short* o = Abf + ((size_t)zz << 22);
        const int i = (xb * 256 + threadIdx.x) * 8;
        const float4 a = *(const float4*)(X + i);
        const float4 b = *(const float4*)(X + i + 4);
        uint4 r;
        r.x = pk_bf16(a.x, a.y); r.y = pk_bf16(a.z, a.w);
        r.z = pk_bf16(b.x, b.y); r.w = pk_bf16(b.z, b.w);
        *(uint4*)(o + i) = r;
    } else {                    // --- wtrans: 1024 blocks per weight ---
        const int wid = bid - 6144;
        const int z = wid >> 10;
        const float* W = z == 0 ? W0 : z == 1 ? W1 : z == 2 ? W2 : W3;
        short* O = Wt + ((size_t)z << 20);
        const int k0 = (wid & 31) * 32, n0 = ((wid >> 5) & 31) * 32;
        const int tx = threadIdx.x & 31, ty = threadIdx.x >> 5;  // (32,8)
        #pragma unroll
        for (int j = 0; j < 32; j += 8)
            tile[ty + j][tx] = W[(k0 + ty + j) * 1024 + n0 + tx];
        __syncthreads();
        #pragma unroll
        for (int j = 0; j < 32; j += 8)
            O[(n0 + ty + j) * 1024 + k0 + tx] = f2bf(tile[tx][ty + j]);
    }
}

// ---------------------------------------------------------------------------
// GEMM core geometry (BM=64, BN=128, BK=32), 4 waves:
// wave w owns rows wr*32 (wr=w>>1), cols wc*64 (wc=w&1): acc[2][4] frags.
// Double-buffered LDS via global_load_lds dwordx4; STAGE(next) before
// compute(cur); one barrier per K-step.
// ---------------------------------------------------------------------------
#define GEMM_CORE(Aa, Ba)                                                     \
    __shared__ short Al[2][2048];   /* [64 m][32 k] */                        \
    __shared__ short Bl[2][4096];   /* [128 n][32 k] */                       \
    const int t = threadIdx.x;                                                \
    const int m0 = blockIdx.y * 64, n0 = blockIdx.x * 128;                    \
    const int lane = t & 63, w = t >> 6;                                      \
    const int lm = lane & 15, lg = lane >> 4;                                 \
    const int wr = w >> 1, wc = w & 1;                                        \
    f32x4 acc[2][4] = {};                                                     \
    STAGE(0, 0);                                                              \
    __syncthreads();                                                          \
    int buf = 0;                                                              \
    for (int kk = 0; kk < 32; ++kk) {                                         \
        if (kk < 31) STAGE(buf ^ 1, (kk + 1) * 32);                           \
        const short* Ab = Al[buf];                                            \
        const short* Bb = Bl[buf];                                            \
        short8 af[2], bfr[4];                                                 \
        _Pragma("unroll")                                                     \
        for (int mf = 0; mf < 2; ++mf)                                        \
            af[mf] = *(const short8*)(Ab + (wr * 32 + mf * 16 + lm) * 32 + lg * 8); \
        _Pragma("unroll")                                                     \
        for (int nf = 0; nf < 4; ++nf)                                        \
            bfr[nf] = *(const short8*)(Bb + (wc * 64 + nf * 16 + lm) * 32 + lg * 8); \
        _Pragma("unroll")                                                     \
        for (int mf = 0; mf < 2; ++mf)                                        \
            _Pragma("unroll")                                                 \
            for (int nf = 0; nf < 4; ++nf)                                    \
                acc[mf][nf] = __builtin_amdgcn_mfma_f32_16x16x32_bf16(        \
                    af[mf], bfr[nf], acc[mf][nf], 0, 0, 0);                   \
        __syncthreads();                                                      \
        buf ^= 1;                                                             \
    }

#define STAGE(buf, k0) do {                                                   \
    gload16(Aa + (size_t)(m0 + (t >> 2)) * 1024 + (k0) + (t & 3) * 8,         \
            &Al[buf][w * 512]);                                               \
    _Pragma("unroll")                                                         \
    for (int j = 0; j < 2; ++j) {                                             \
        const int c = j * 256 + t;                                            \
        gload16(Ba + (size_t)(n0 + (c >> 2)) * 1024 + (k0) + (c & 3) * 8,     \
                &Bl[buf][j * 2048 + w * 512]);                                \
    }                                                                         \
} while (0)

// ---------------------------------------------------------------------------
// Merged Q/K/V projection GEMM. Grid (8, 64, 3) = 1536 blocks = 6/CU.
// ---------------------------------------------------------------------------
__global__ __launch_bounds__(256) void gemmqkv(
    const short* __restrict__ Abase, const short* __restrict__ Wt,
    const float* __restrict__ bq, const float* __restrict__ bk,
    const float* __restrict__ bv, short* __restrict__ Qh,
    short* __restrict__ Kh, short* __restrict__ Vt, float qscale)
{
    const int z = blockIdx.z;
    const short* Aa = Abase + ((size_t)z << 22);
    const short* Ba = Wt + ((size_t)z << 20);
    const float* bias = z == 0 ? bq : z == 1 ? bk : bv;
    short* O = z == 0 ? Qh : z == 1 ? Kh : Vt;
    const float scale = z == 0 ? qscale : 1.0f;

    GEMM_CORE(Aa, Ba)

    #pragma unroll
    for (int mf = 0; mf < 2; ++mf) {
        const int mb = m0 + wr * 32 + mf * 16 + lg * 4;
        #pragma unroll
        for (int nf = 0; nf < 4; ++nf) {
            const int n = n0 + wc * 64 + nf * 16 + lm;
            const float bs = bias[n];
            if (z == 2) {   // V^T [B,H,64,S]: 4 consecutive s per lane
                short4v sv;
                #pragma unroll
                for (int i = 0; i < 4; ++i)
                    sv[i] = f2bf(acc[mf][nf][i] + bs);
                const int addr = (((mb >> 11) * 16 + (n >> 6)) * 64 + (n & 63)) * 2048 + (mb & 2047);
                *(short4v*)&O[addr] = sv;
            } else {        // head-split [B,H,S,64]
                #pragma unroll
                for (int i = 0; i < 4; ++i) {
                    const int m = mb + i;
                    const int addr = (((m >> 11) * 16 + (n >> 6)) * 2048 + (m & 2047)) * 64 + (n & 63);
                    O[addr] = f2bf(scale * (acc[mf][nf][i] + bs));
                }
            }
        }
    }
}

// ---------------------------------------------------------------------------
// Final projection: out = Ctx @ Wo^T + bo, f32 flat. Grid (8,64) = 512 blocks.
// ---------------------------------------------------------------------------
__global__ __launch_bounds__(256) void gemmo(
    const short* __restrict__ Aa, const short* __restrict__ Ba,
    const float* __restrict__ bias, float* __restrict__ Out)
{
    GEMM_CORE(Aa, Ba)

    #pragma unroll
    for (int mf = 0; mf < 2; ++mf) {
        const int mb = m0 + wr * 32 + mf * 16 + lg * 4;
        #pragma unroll
        for (int nf = 0; nf < 4; ++nf) {
            const int n = n0 + wc * 64 + nf * 16 + lm;
            const float bs = bias[n];
            #pragma unroll
            for (int i = 0; i < 4; ++i)
                Out[(mb + i) * 1024 + n] = acc[mf][nf][i] + bs;
        }
    }
}
#undef STAGE
#undef GEMM_CORE

// ---------------------------------------------------------------------------
// Flash attention v7: v6 + softmax sum moved onto the matrix pipe.
//  - row-sum of P computed by mfma(ones_frag, pf, o_sum) appended to each PV
//    half (4 extra MFMA/tile on the 19%-utilized matrix pipe) — replaces the
//    32-add + 2-shfl VALU sum reduction. Denominator now sums the EXACT bf16
//    P values used in PV. Defer-max rescale multiplies o_sum by alpha, so
//    online-softmax algebra is preserved (first tile: alpha=0 zeroes it).
//  - max reduce restructured as a pairwise tree (nested fmaxf -> v_max3_f32).
// Unchanged vs v6: 8 waves x 16 q-rows, KVBLK=128/barrier, V tile as two
// [64][64] halves, XOR chunk swizzle, double-buffer + T14 early loads,
// 1 barrier/tile, swapped QK^T / PV, exp2-domain softmax, defer-max (T13).
// LDS 80KB -> 2 blocks/CU.
// ---------------------------------------------------------------------------
__global__ __launch_bounds__(512, 4) void attn_k(
    const short* __restrict__ Q, const short* __restrict__ K,
    const short* __restrict__ V, short* __restrict__ Ctx)
{
    __shared__ short Kl[2][128][64];
    __shared__ short Vl[2][2][64][64];   // [buf][key-half][d-row][key-chunk]
    __shared__ short Pl[8][16][64];
    const int t = threadIdx.x;
    const int qt = blockIdx.x, bh = blockIdx.y;
    const int lane = t & 63, w = t >> 6;   // 8 waves
    const int lm = lane & 15, lg = lane >> 4;
    const int swz = (lm & 7) << 3;          // P-buffer swizzle (shorts)
    const int swc = lm & 7;                 // K/V read chunk swizzle

    const int qrow = qt * 128 + w * 16 + lm;
    short8 qf[2];
    #pragma unroll
    for (int ks = 0; ks < 2; ++ks)
        qf[ks] = *(const short8*)(Q + ((size_t)bh * 2048 + qrow) * 64 + ks * 32 + lg * 8);

    const short ob = (short)0x3F80;   // bf16 1.0
    const short8 ones = {ob, ob, ob, ob, ob, ob, ob, ob};

    float m_run = -3e38f;
    f32x4 o_acc[4] = {};
    f32x4 o_sum = {};                 // all 4 elems = running softmax denom

    // staging: thread t owns K row rk (chunks 2ck,2ck+1 of 8) and V d-row rv
    // (chunks 2cv,2cv+1 of 16; both land in key-half cv>>2)
    const int rk = t >> 2, ck = t & 3;
    const int rv = t >> 3, cv = t & 7;
    const short* Kg = K + ((size_t)bh * 2048 + rk) * 64 + ck * 16;
    const short* Vg = V + ((size_t)bh * 64 + rv) * 2048 + cv * 16;
    const int koff0 = rk * 64 + ((ck * 2) ^ (rk & 7)) * 8;
    const int koff1 = rk * 64 + ((ck * 2 + 1) ^ (rk & 7)) * 8;
    const int vhalf = (cv >> 2) * 4096;
    const int voff0 = vhalf + rv * 64 + (((cv * 2) & 7) ^ (rv & 7)) * 8;
    const int voff1 = vhalf + rv * 64 + (((cv * 2 + 1) & 7) ^ (rv & 7)) * 8;

    {   // prologue: stage tile 0 into buffer 0
        short8 a = *(const short8*)(Kg);
        short8 b = *(const short8*)(Kg + 8);
        short8 c = *(const short8*)(Vg);
        short8 d = *(const short8*)(Vg + 8);
        *(short8*)((short*)Kl[0] + koff0) = a;
        *(short8*)((short*)Kl[0] + koff1) = b;
        *(short8*)((short*)Vl[0] + voff0) = c;
        *(short8*)((short*)Vl[0] + voff1) = d;
    }

    short* prow = &Pl[w][lm][0];
    int cur = 0;

    for (int kt = 0; kt < 16; ++kt) {
        __syncthreads();   // stage[cur] visible; [cur^1] free for writing

        // early-issue global loads for tile kt+1 (T14)
        short8 kn0, kn1, vn0, vn1;
        const bool pfn = (kt < 15);
        if (pfn) {
            const short* Kgn = Kg + (size_t)(kt + 1) * 8192;   // 128 rows * 64
            const short* Vgn = Vg + (kt + 1) * 128;
            kn0 = *(const short8*)(Kgn);
            kn1 = *(const short8*)(Kgn + 8);
            vn0 = *(const short8*)(Vgn);
            vn1 = *(const short8*)(Vgn + 8);
        }

        const short* Kc = (const short*)Kl[cur];
        const short* Vc = (const short*)Vl[cur];

        // ---- S^T = K Q^T, BOTH halves: lane holds q=lm, 32 key-vals ----
        f32x4 sa[2][4] = {};
        #pragma unroll
        for (int h = 0; h < 2; ++h)
            #pragma unroll
            for (int nf = 0; nf < 4; ++nf) {
                const int rr = h * 64 + nf * 16 + lm;
                #pragma unroll
                for (int ks = 0; ks < 2; ++ks) {
                    const short8 kf = *(const short8*)(Kc + rr * 64 + ((ks * 4 + lg) ^ swc) * 8);
                    sa[h][nf] = __builtin_amdgcn_mfma_f32_16x16x32_bf16(kf, qf[ks], sa[h][nf], 0, 0, 0);
                }
            }

        // ---- max reduce: pairwise tree (fmaxf nests fuse to v_max3) ----
        float mx[8];
        #pragma unroll
        for (int h = 0; h < 2; ++h)
            #pragma unroll
            for (int nf = 0; nf < 4; ++nf) {
                const f32x4 v = sa[h][nf];
                mx[h * 4 + nf] = fmaxf(fmaxf(v[0], v[1]), fmaxf(v[2], v[3]));
            }
        float ta = fmaxf(fmaxf(mx[0], mx[1]), fmaxf(mx[2], mx[3]));
        float tb = fmaxf(fmaxf(mx[4], mx[5]), fmaxf(mx[6], mx[7]));
        float mt = fmaxf(ta, tb);
        mt = fmaxf(mt, __shfl_xor(mt, 16));
        mt = fmaxf(mt, __shfl_xor(mt, 32));
        if (__any(mt > m_run + 8.0f)) {     // defer-max (T13)
            const float mn = fmaxf(m_run, mt);
            const float alpha = exp2f(m_run - mn);
            #pragma unroll
            for (int nf = 0; nf < 4; ++nf)
                #pragma unroll
                for (int i = 0; i < 4; ++i)
                    o_acc[nf][i] *= alpha;
            #pragma unroll
            for (int i = 0; i < 4; ++i)
                o_sum[i] *= alpha;
            m_run = mn;
        }
        // exp2 (sum comes from the ones-MFMA below, not a VALU reduction)
        #pragma unroll
        for (int h = 0; h < 2; ++h)
            #pragma unroll
            for (int nf = 0; nf < 4; ++nf)
                #pragma unroll
                for (int i = 0; i < 4; ++i)
                    sa[h][nf][i] = exp2f(sa[h][nf][i] - m_run);

        // ---- per key-half: P-pack -> pf -> PV + ones row-sum ----
        #pragma unroll
        for (int h = 0; h < 2; ++h) {
            #pragma unroll
            for (int nf = 0; nf < 4; ++nf) {
                uint2 pv;
                pv.x = pk_bf16(sa[h][nf][0], sa[h][nf][1]);
                pv.y = pk_bf16(sa[h][nf][2], sa[h][nf][3]);
                *(uint2*)(prow + ((nf * 16 + lg * 4) ^ swz)) = pv;
            }
            short8 pf[2];
            #pragma unroll
            for (int ks = 0; ks < 2; ++ks)
                pf[ks] = *(const short8*)(prow + ((ks * 32 + lg * 8) ^ swz));

            // late ds_write of tile kt+1 (between the two PV halves)
            if (h == 0 && pfn) {
                short* Kn = (short*)Kl[cur ^ 1];
                short* Vn = (short*)Vl[cur ^ 1];
                *(short8*)(Kn + koff0) = kn0;
                *(short8*)(Kn + koff1) = kn1;
                *(short8*)(Vn + voff0) = vn0;
                *(short8*)(Vn + voff1) = vn1;
            }

            // ctx^T += V^T P^T ; denom += ones . P^T (matrix-pipe row-sum)
            #pragma unroll
            for (int nf = 0; nf < 4; ++nf) {
                const int rr = nf * 16 + lm;
                #pragma unroll
                for (int ks = 0; ks < 2; ++ks) {
                    const short8 vf = *(const short8*)(Vc + h * 4096 + rr * 64 + ((ks * 4 + lg) ^ swc) * 8);
                    o_acc[nf] = __builtin_amdgcn_mfma_f32_16x16x32_bf16(vf, pf[ks], o_acc[nf], 0, 0, 0);
                }
            }
            o_sum = __builtin_amdgcn_mfma_f32_16x16x32_bf16(ones, pf[0], o_sum, 0, 0, 0);
            o_sum = __builtin_amdgcn_mfma_f32_16x16x32_bf16(ones, pf[1], o_sum, 0, 0, 0);
        }
        cur ^= 1;
    }

    // epilogue: ctx[b][q][h*64 + d] bf16, 8B vector writes
    const float inv = 1.f / o_sum[0];
    const int b = bh >> 4, h = bh & 15;
    short* outp = Ctx + ((size_t)b * 2048 + qrow) * 1024 + h * 64 + lg * 4;
    #pragma unroll
    for (int nf = 0; nf < 4; ++nf) {
        uint2 pk;
        pk.x = pk_bf16(o_acc[nf][0] * inv, o_acc[nf][1] * inv);
        pk.y = pk_bf16(o_acc[nf][2] * inv, o_acc[nf][3] * inv);
        *(uint2*)(outp + nf * 16) = pk;
    }
}

// ---------------------------------------------------------------------------
extern "C" void kernel_launch(void* const* d_in, const int* in_sizes, int n_in,
                              void* d_out, int out_size, void* d_ws, size_t ws_size,
                              hipStream_t stream)
{
    const float* query  = (const float*)d_in[0];
    const float* key_in = (const float*)d_in[1];
    const float* value  = (const float*)d_in[2];
    const float* Wq = (const float*)d_in[3];
    const float* bq = (const float*)d_in[4];
    const float* Wk = (const float*)d_in[5];
    const float* bk = (const float*)d_in[6];
    const float* Wv = (const float*)d_in[7];
    const float* bv = (const float*)d_in[8];
    const float* Wo = (const float*)d_in[9];
    const float* bo = (const float*)d_in[10];
    float* out = (float*)d_out;

    char* ws = (char*)d_ws;
    short* Wt  = (short*)(ws);               // 4 x 2MB transposed bf16 weights
    short* Abf = (short*)(ws + (8  << 20));  // 3 x 8MB bf16 inputs (q,k,v)
    short* Qh  = (short*)(ws + (32 << 20));  // [B,H,S,64] 8MB (scaled 0.125*log2e)
    short* Kh  = (short*)(ws + (40 << 20));  // [B,H,S,64] 8MB
    short* Vt  = (short*)(ws + (48 << 20));  // [B,H,64,S] 8MB
    short* Ctx = Abf;                        // Abf dead after QKV gemm; alias

    const float qscale = 0.125f * 1.44269504088896f;  // 1/sqrt(64) * log2(e)

    hipLaunchKernelGGL(prep, dim3(10240), dim3(256), 0, stream,
                       query, key_in, value, Abf, Wq, Wk, Wv, Wo, Wt);
    hipLaunchKernelGGL(gemmqkv, dim3(8, 64, 3), dim3(256), 0, stream,
                       Abf, Wt, bq, bk, bv, Qh, Kh, Vt, qscale);
    hipLaunchKernelGGL(attn_k, dim3(16, 32), dim3(512), 0, stream,
                       Qh, Kh, Vt, Ctx);
    hipLaunchKernelGGL(gemmo, dim3(8, 64), dim3(256), 0, stream,
                       Ctx, Wt + (3 << 20), bo, out);
}